// Round 9
// baseline (356.441 us; speedup 1.0000x reference)
//
#include <hip/hip_runtime.h>
#include <hip/hip_bf16.h>
#include <cstdint>
#include <cstddef>

typedef __attribute__((ext_vector_type(8))) short s16x8;
typedef __attribute__((ext_vector_type(4))) float f32x4;

#define CAP 64   // padded-CSR slots/node; P(Poisson(16) >= 64) ~ 1e-19

static __device__ __forceinline__ float u2f(unsigned int u) {
    union { unsigned int i; float f; } c; c.i = u; return c.f;
}
static __device__ __forceinline__ unsigned short f2b(float f) {
    union { float f; unsigned int i; } c; c.f = f;
    unsigned int x = c.i;
    x += 0x7fffu + ((x >> 16) & 1u);   // round-to-nearest-even
    return (unsigned short)(x >> 16);
}

// unpack one 16B bf16x8 chunk and accumulate into 8 fp32 lanes-features
static __device__ __forceinline__ void acc8(float* acc, const int4& t) {
    acc[0] += u2f(((unsigned)t.x) << 16);
    acc[1] += u2f(((unsigned)t.x) & 0xffff0000u);
    acc[2] += u2f(((unsigned)t.y) << 16);
    acc[3] += u2f(((unsigned)t.y) & 0xffff0000u);
    acc[4] += u2f(((unsigned)t.z) << 16);
    acc[5] += u2f(((unsigned)t.z) & 0xffff0000u);
    acc[6] += u2f(((unsigned)t.w) << 16);
    acc[7] += u2f(((unsigned)t.w) & 0xffff0000u);
}

// ---------------- padded-CSR build: ONE atomic pass (unchanged) ----------------
__global__ void build_kernel(const int* __restrict__ src, const int* __restrict__ dst,
                             int E, int* __restrict__ cnt, int* __restrict__ colp) {
    const int base = blockIdx.x * 1024 + threadIdx.x;
    int d[4], s[4];
    bool ok[4];
#pragma unroll
    for (int k = 0; k < 4; k++) {
        const int i = base + k * 256;
        ok[k] = (i < E);
        d[k] = ok[k] ? dst[i] : 0;
        s[k] = ok[k] ? src[i] : 0;
    }
    int p[4];
#pragma unroll
    for (int k = 0; k < 4; k++)
        if (ok[k]) p[k] = atomicAdd(&cnt[d[k]], 1);
#pragma unroll
    for (int k = 0; k < 4; k++)
        if (ok[k] && p[k] < CAP) colp[d[k] * CAP + p[k]] = s[k];
}

// -- merged prep: x->bf16 + both Bt builds + cnt zeroing + zero-rows (1 launch) --
__global__ __launch_bounds__(256) void prep_kernel(const float* __restrict__ x,
                                                   unsigned short* __restrict__ xb, int n4, int nbc,
                                                   const float* __restrict__ W1l, const float* __restrict__ W1r,
                                                   unsigned short* __restrict__ Bt1,
                                                   const float* __restrict__ W2l, const float* __restrict__ W2r,
                                                   unsigned short* __restrict__ Bt2,
                                                   int* __restrict__ cnt, int N,
                                                   unsigned short* __restrict__ hb) {
    const int b = blockIdx.x;
    if (b < nbc) {
        const int i = b * 256 + threadIdx.x;
        if (i < n4) {
            float4 v = *(const float4*)(x + (size_t)i * 4);
            ushort4 o;
            o.x = f2b(v.x); o.y = f2b(v.y); o.z = f2b(v.z); o.w = f2b(v.w);
            *(ushort4*)(xb + (size_t)i * 4) = o;
        }
    } else if (b < nbc + 1024) {
        const int job = b - nbc;            // 0..1023; 512 blocks per Bt
        const int idx = (job & 511) * 256 + threadIdx.x;
        const float* Wl = (job < 512) ? W1l : W2l;
        const float* Wr = (job < 512) ? W1r : W2r;
        unsigned short* Bt = (job < 512) ? Bt1 : Bt2;
        const int n = idx >> 9;
        const int k = idx & 511;
        float v = (k < 256) ? Wl[(size_t)k * 256 + n] : Wr[(size_t)(k - 256) * 256 + n];
        Bt[idx] = f2b(v);
    } else if (b < nbc + 1024 + (N + 255) / 256) {
        const int i = (b - nbc - 1024) * 256 + threadIdx.x;
        if (i < N) cnt[i] = 0;
    } else {
        // zero-row N of xb and hb (backing store for invalid edge slots)
        const int i = threadIdx.x;
        xb[(size_t)N * 256 + i] = 0;
        hb[(size_t)N * 256 + i] = 0;
    }
}

// ---------------- mean aggregation (padded CSR, no atomics) ----------------
// KEY CHANGE (safe MLP test): gathers staged via global_load_lds DMA.
// Round-8's VGPR-targeted asm burst corrupted data (regalloc copies read
// dest regs before the load landed -> NaN). DMA-to-LDS has NO destination
// VGPRs: neither scheduler nor regalloc can re-serialize or corrupt it, and
// outstanding depth is controlled exactly by counted vmcnt (same machinery
// the gemm uses correctly). Slot u of a wave's 16KB region holds edges 2u
// (lanes 0-31) and 2u+1 (lanes 32-63); lane l DMA-writes base+u*1024+l*16
// and reads back exactly its own 16B -> conflict-free, unpack order per lane
// identical to rounds 0-7 -> bit-identical. deg>32 tail keeps the plain
// register path (passing, rare). 1 node/wave, 4 waves/block, 64KB LDS.
__global__ __launch_bounds__(256) void aggregate_kernel(const unsigned short* __restrict__ xb,
                                                        const int* __restrict__ cnt,
                                                        const int* __restrict__ colp,
                                                        unsigned short* __restrict__ mean,
                                                        int N) {
    __shared__ unsigned short smem[4][8192];   // per wave: 16 slots x 1KB
    const int wave = threadIdx.x >> 6;
    const int n = blockIdx.x * 4 + wave;
    if (n >= N) return;                        // no barriers in kernel: safe
    const int lane = threadIdx.x & 63;
    const int h = lane >> 5;       // which edge of the pair
    const int l31 = lane & 31;     // features [8*l31, 8*l31+8)
    const int degT = cnt[n];
    const int degS = degT < CAP ? degT : CAP;

    int idx = N;                   // default -> zero row
    if (lane < degS) idx = colp[n * CAP + lane];
    const unsigned short* basep = xb + l31 * 8;

    const bool big = (degS > 16);  // wave-uniform

    // hoist ALL cross-lane index gathers ahead of the loads
    int cidx[16];
#pragma unroll
    for (int u = 0; u < 16; u++) cidx[u] = __shfl(idx, 2 * u + h);

    char* lds = (char*)&smem[wave][0];

    // issue DMA burst: slots 0..7 (edges 0..15), plus 8..15 when deg>16
#pragma unroll
    for (int u = 0; u < 8; u++)
        __builtin_amdgcn_global_load_lds(
            (const __attribute__((address_space(1))) void*)(basep + (size_t)cidx[u] * 256),
            (__attribute__((address_space(3))) void*)(lds + u * 1024), 16, 0, 0);
    if (big) {
#pragma unroll
        for (int u = 8; u < 16; u++)
            __builtin_amdgcn_global_load_lds(
                (const __attribute__((address_space(1))) void*)(basep + (size_t)cidx[u] * 256),
                (__attribute__((address_space(3))) void*)(lds + u * 1024), 16, 0, 0);
    }

    float acc[8];
#pragma unroll
    for (int k = 0; k < 8; k++) acc[k] = 0.f;

    // lane reads back its own 16B per slot: lds + u*1024 + lane*16
    if (big) {
        asm volatile("s_waitcnt vmcnt(8)" ::: "memory");   // slots 0..7 landed
        __builtin_amdgcn_sched_barrier(0);
#pragma unroll
        for (int u = 0; u < 8; u++)
            acc8(acc, *(const int4*)(lds + u * 1024 + lane * 16));
        asm volatile("s_waitcnt vmcnt(0)" ::: "memory");   // slots 8..15 landed
        __builtin_amdgcn_sched_barrier(0);
#pragma unroll
        for (int u = 8; u < 16; u++)
            acc8(acc, *(const int4*)(lds + u * 1024 + lane * 16));
    } else {
        asm volatile("s_waitcnt vmcnt(0)" ::: "memory");
        __builtin_amdgcn_sched_barrier(0);
#pragma unroll
        for (int u = 0; u < 8; u++)
            acc8(acc, *(const int4*)(lds + u * 1024 + lane * 16));
    }

    // rare tail (deg > 32): plain register path (round-7, passing)
#pragma unroll 1
    for (int base = 32; base < degS; base += 16) {
        int cw[8];
#pragma unroll
        for (int u = 0; u < 8; u++) cw[u] = __shfl(idx, base + 2 * u + h);
        int4 w[8];
#pragma unroll
        for (int u = 0; u < 8; u++) w[u] = *(const int4*)(basep + (size_t)cw[u] * 256);
        __builtin_amdgcn_sched_barrier(0);
#pragma unroll
        for (int u = 0; u < 8; u++) acc8(acc, w[u]);
    }

#pragma unroll
    for (int k = 0; k < 8; k++) acc[k] += __shfl_xor(acc[k], 32);

    if (h == 0) {
        const float inv = 1.0f / (float)(degT > 0 ? degT : 1);
        union { unsigned short us[8]; int4 v; } o;
#pragma unroll
        for (int k = 0; k < 8; k++) o.us[k] = f2b(acc[k] * inv);
        *(int4*)(mean + (size_t)n * 256 + l31 * 8) = o.v;
    }
}

// ---------------- fused GEMM: C = [A0 | A1] @ Bt^T + bias (unchanged r5) ------
// 128x128 tile, BK=64, 2-deep counted-vmcnt pipeline, 8-seg XOR swizzle
// (conflicts==0), setprio around MFMA cluster, LDS-repacked epilogue.
template <int RELU>
__global__ __launch_bounds__(256) void gemm_kernel(const unsigned short* __restrict__ A0,
                                                   const unsigned short* __restrict__ A1,
                                                   const unsigned short* __restrict__ Bt,
                                                   const float* __restrict__ bias,
                                                   float* __restrict__ outF,
                                                   unsigned short* __restrict__ outB,
                                                   int M) {
    __shared__ unsigned short smem[4][128 * 64];   // [0..1]=A bufs, [2..3]=B bufs
    const int tid = threadIdx.x;
    const int m0 = blockIdx.x * 128;
    const int n0 = blockIdx.y * 128;
    const int wave = tid >> 6, lane = tid & 63;
    const int wm = (wave >> 1) * 64, wn = (wave & 1) * 64;
    const int lr = lane & 15, lg = lane >> 4;

    const int r8 = lane >> 3;                       // row-within-8
    const int koffs = ((lane & 7) ^ r8) * 8;        // pre-swizzled k-offset (shorts)
    int arow[4], brow[4];
#pragma unroll
    for (int q = 0; q < 4; q++) {
        int r = m0 + (wave * 4 + q) * 8 + r8;
        arow[q] = (r < M) ? r : (M - 1);
        brow[q] = n0 + (wave * 4 + q) * 8 + r8;
    }

    f32x4 acc[4][4];
#pragma unroll
    for (int i = 0; i < 4; i++)
#pragma unroll
        for (int j = 0; j < 4; j++) acc[i][j] = (f32x4)0.0f;

    auto stage = [&](int buf, int kt) {
        const int k0 = kt * 64;
        const unsigned short* Asrc = (k0 < 256) ? A0 : A1;
        const int kk = k0 & 255;
        char* asb = (char*)(&smem[buf][0]);
        char* bsb = (char*)(&smem[2 + buf][0]);
#pragma unroll
        for (int q = 0; q < 4; q++)
            __builtin_amdgcn_global_load_lds(
                (const __attribute__((address_space(1))) void*)(Asrc + (size_t)arow[q] * 256 + kk + koffs),
                (__attribute__((address_space(3))) void*)(asb + (wave * 4 + q) * 1024), 16, 0, 0);
#pragma unroll
        for (int q = 0; q < 4; q++)
            __builtin_amdgcn_global_load_lds(
                (const __attribute__((address_space(1))) void*)(Bt + (size_t)brow[q] * 512 + k0 + koffs),
                (__attribute__((address_space(3))) void*)(bsb + (wave * 4 + q) * 1024), 16, 0, 0);
    };

    stage(0, 0);
    stage(1, 1);

#pragma unroll 1
    for (int t = 0; t < 8; t++) {
        if (t < 7) asm volatile("s_waitcnt vmcnt(8)" ::: "memory");
        else       asm volatile("s_waitcnt vmcnt(0)" ::: "memory");
        __builtin_amdgcn_s_barrier();          // all waves' tile-t loads landed
        asm volatile("" ::: "memory");
        __builtin_amdgcn_sched_barrier(0);

        const int cur = t & 1;
        s16x8 a[2][4], b[2][4];
#pragma unroll
        for (int ks = 0; ks < 2; ks++)
#pragma unroll
            for (int i = 0; i < 4; i++) {
                const int row = wm + i * 16 + lr;
                const int u = (ks * 4 + lg) ^ (lr & 7);
                a[ks][i] = *(const s16x8*)(&smem[cur][row * 64 + u * 8]);
            }
#pragma unroll
        for (int ks = 0; ks < 2; ks++)
#pragma unroll
            for (int j = 0; j < 4; j++) {
                const int row = wn + j * 16 + lr;
                const int u = (ks * 4 + lg) ^ (lr & 7);
                b[ks][j] = *(const s16x8*)(&smem[2 + cur][row * 64 + u * 8]);
            }

        asm volatile("s_waitcnt lgkmcnt(0)" ::: "memory");
        __builtin_amdgcn_sched_barrier(0);
        __builtin_amdgcn_s_barrier();          // all waves done reading buf[cur]
        asm volatile("" ::: "memory");
        __builtin_amdgcn_sched_barrier(0);

        if (t < 6) stage(cur, t + 2);          // refill freed buffer behind MFMA

        __builtin_amdgcn_s_setprio(1);
#pragma unroll
        for (int ks = 0; ks < 2; ks++)
#pragma unroll
            for (int i = 0; i < 4; i++)
#pragma unroll
                for (int j = 0; j < 4; j++)
                    acc[i][j] = __builtin_amdgcn_mfma_f32_16x16x32_bf16(a[ks][i], b[ks][j], acc[i][j], 0, 0, 0);
        __builtin_amdgcn_s_setprio(0);
    }

    // ---- epilogue: per-wave LDS repack -> coalesced stores ----
    float* wbase = ((float*)&smem[0][0]) + wave * 2304;
#pragma unroll
    for (int hf = 0; hf < 2; hf++) {
#pragma unroll
        for (int j2 = 0; j2 < 2; j2++) {
            const int j = hf * 2 + j2;
            const int n = n0 + wn + j * 16 + lr;
            const float bv = bias[n];
#pragma unroll
            for (int i = 0; i < 4; i++)
#pragma unroll
                for (int r = 0; r < 4; r++) {
                    const int row = i * 16 + lg * 4 + r;
                    float v = acc[i][j][r] + bv;
                    if (RELU) v = fmaxf(v, 0.0f);
                    wbase[row * 36 + j2 * 16 + lr] = v;
                }
        }
        asm volatile("s_waitcnt lgkmcnt(0)" ::: "memory");
        __builtin_amdgcn_sched_barrier(0);
        if (RELU) {
#pragma unroll
            for (int c = 0; c < 4; c++) {
                const int row = (lane >> 2) + 16 * c;
                const int col8 = (lane & 3) * 8;
                const int gm = m0 + wm + row;
                f32x4 t0 = *(f32x4*)(wbase + row * 36 + col8);
                f32x4 t1 = *(f32x4*)(wbase + row * 36 + col8 + 4);
                union { unsigned short us[8]; int4 v; } o;
#pragma unroll
                for (int q = 0; q < 4; q++) { o.us[q] = f2b(t0[q]); o.us[4 + q] = f2b(t1[q]); }
                if (gm < M)
                    *(int4*)(outB + (size_t)gm * 256 + n0 + wn + hf * 32 + col8) = o.v;
            }
        } else {
#pragma unroll
            for (int c = 0; c < 8; c++) {
                const int row = (lane >> 3) + 8 * c;
                const int col4 = (lane & 7) * 4;
                const int gm = m0 + wm + row;
                f32x4 t = *(f32x4*)(wbase + row * 36 + col4);
                if (gm < M)
                    *(f32x4*)(outF + (size_t)gm * 256 + n0 + wn + hf * 32 + col4) = t;
            }
        }
        asm volatile("s_waitcnt lgkmcnt(0)" ::: "memory");
        __builtin_amdgcn_sched_barrier(0);
    }
}

extern "C" void kernel_launch(void* const* d_in, const int* in_sizes, int n_in,
                              void* d_out, int out_size, void* d_ws, size_t ws_size,
                              hipStream_t stream) {
    const float* x   = (const float*)d_in[0];
    const int*   ei  = (const int*)d_in[1];
    const float* W1l = (const float*)d_in[2];
    const float* b1  = (const float*)d_in[3];
    const float* W1r = (const float*)d_in[4];
    const float* W2l = (const float*)d_in[5];
    const float* b2  = (const float*)d_in[6];
    const float* W2r = (const float*)d_in[7];
    float* out = (float*)d_out;

    const int N = in_sizes[0] / 256;   // 50000
    const int E = in_sizes[1] / 2;     // 800000
    const int* src = ei;
    const int* dst = ei + E;

    char* ws = (char*)d_ws;
    size_t off = 0;
    auto alloc = [&](size_t bytes) -> void* {
        void* p = ws + off;
        off += (bytes + 255) & ~(size_t)255;
        return p;
    };
    int* cnt  = (int*)alloc((size_t)N * 4);
    int* colp = (int*)alloc((size_t)N * CAP * 4);
    unsigned short* xb  = (unsigned short*)alloc((size_t)(N + 1) * 256 * 2);  // +zero row
    unsigned short* hb  = (unsigned short*)alloc((size_t)(N + 1) * 256 * 2);  // +zero row
    unsigned short* mb  = (unsigned short*)alloc((size_t)N * 256 * 2);
    unsigned short* Bt1 = (unsigned short*)alloc((size_t)256 * 512 * 2);
    unsigned short* Bt2 = (unsigned short*)alloc((size_t)256 * 512 * 2);

    // merged prep: x->bf16 + Bt builds + cnt zeroing + zero-rows
    const int n4 = N * 256 / 4;
    const int nbc = (n4 + 255) / 256;
    const int nzb = (N + 255) / 256;
    prep_kernel<<<nbc + 1024 + nzb + 1, 256, 0, stream>>>(x, xb, n4, nbc,
                                                          W1l, W1r, Bt1, W2l, W2r, Bt2,
                                                          cnt, N, hb);

    // padded-CSR build: one atomic pass (after cnt zeroed by prep)
    build_kernel<<<(E + 1023) / 1024, 256, 0, stream>>>(src, dst, E, cnt, colp);

    const int mtiles = (N + 127) / 128;
    dim3 ggrid(mtiles, 2);
    const int ablocks = (N + 3) / 4;

    // layer 1: mean(x) -> mb; h = relu([mb|xb] @ Bt1 + b1) -> hb (bf16)
    aggregate_kernel<<<ablocks, 256, 0, stream>>>(xb, cnt, colp, mb, N);
    gemm_kernel<1><<<ggrid, 256, 0, stream>>>(mb, xb, Bt1, b1, nullptr, hb, N);

    // layer 2: mean(h) -> mb; out = [mb|hb] @ Bt2 + b2 (fp32)
    aggregate_kernel<<<ablocks, 256, 0, stream>>>(hb, cnt, colp, mb, N);
    gemm_kernel<0><<<ggrid, 256, 0, stream>>>(mb, hb, Bt2, b2, out, nullptr, N);
}

// Round 10
// 283.478 us; speedup vs baseline: 1.2574x; 1.2574x over previous
//
#include <hip/hip_runtime.h>
#include <hip/hip_bf16.h>
#include <cstdint>
#include <cstddef>

typedef __attribute__((ext_vector_type(8))) short s16x8;
typedef __attribute__((ext_vector_type(4))) float f32x4;
typedef __attribute__((ext_vector_type(2))) float f32x2;

#define CAP 64   // padded-CSR slots/node; P(Poisson(16) >= 64) ~ 1e-19

static __device__ __forceinline__ float u2f(unsigned int u) {
    union { unsigned int i; float f; } c; c.i = u; return c.f;
}
static __device__ __forceinline__ unsigned short f2b(float f) {
    union { float f; unsigned int i; } c; c.f = f;
    unsigned int x = c.i;
    x += 0x7fffu + ((x >> 16) & 1u);   // round-to-nearest-even
    return (unsigned short)(x >> 16);
}

// unpack one 16B fp8x16 chunk (e4m3) and accumulate into 16 fp32 features
static __device__ __forceinline__ void acc16f8(float* acc, const int4& t) {
    f32x2 p;
    p = __builtin_amdgcn_cvt_pk_f32_fp8(t.x, false); acc[0]  += p.x; acc[1]  += p.y;
    p = __builtin_amdgcn_cvt_pk_f32_fp8(t.x, true);  acc[2]  += p.x; acc[3]  += p.y;
    p = __builtin_amdgcn_cvt_pk_f32_fp8(t.y, false); acc[4]  += p.x; acc[5]  += p.y;
    p = __builtin_amdgcn_cvt_pk_f32_fp8(t.y, true);  acc[6]  += p.x; acc[7]  += p.y;
    p = __builtin_amdgcn_cvt_pk_f32_fp8(t.z, false); acc[8]  += p.x; acc[9]  += p.y;
    p = __builtin_amdgcn_cvt_pk_f32_fp8(t.z, true);  acc[10] += p.x; acc[11] += p.y;
    p = __builtin_amdgcn_cvt_pk_f32_fp8(t.w, false); acc[12] += p.x; acc[13] += p.y;
    p = __builtin_amdgcn_cvt_pk_f32_fp8(t.w, true);  acc[14] += p.x; acc[15] += p.y;
}

// ---------------- padded-CSR build: ONE atomic pass (unchanged) ----------------
__global__ void build_kernel(const int* __restrict__ src, const int* __restrict__ dst,
                             int E, int* __restrict__ cnt, int* __restrict__ colp) {
    const int base = blockIdx.x * 1024 + threadIdx.x;
    int d[4], s[4];
    bool ok[4];
#pragma unroll
    for (int k = 0; k < 4; k++) {
        const int i = base + k * 256;
        ok[k] = (i < E);
        d[k] = ok[k] ? dst[i] : 0;
        s[k] = ok[k] ? src[i] : 0;
    }
    int p[4];
#pragma unroll
    for (int k = 0; k < 4; k++)
        if (ok[k]) p[k] = atomicAdd(&cnt[d[k]], 1);
#pragma unroll
    for (int k = 0; k < 4; k++)
        if (ok[k] && p[k] < CAP) colp[d[k] * CAP + p[k]] = s[k];
}

// -- merged prep: x->bf16 + x->fp8 + Bt builds + cnt zero + fp8 zero-rows -------
__global__ __launch_bounds__(256) void prep_kernel(const float* __restrict__ x,
                                                   unsigned short* __restrict__ xb,
                                                   unsigned char* __restrict__ xb8,
                                                   int n4, int nbc,
                                                   const float* __restrict__ W1l, const float* __restrict__ W1r,
                                                   unsigned short* __restrict__ Bt1,
                                                   const float* __restrict__ W2l, const float* __restrict__ W2r,
                                                   unsigned short* __restrict__ Bt2,
                                                   int* __restrict__ cnt, int N,
                                                   unsigned char* __restrict__ hb8) {
    const int b = blockIdx.x;
    if (b < nbc) {
        const int i = b * 256 + threadIdx.x;
        if (i < n4) {
            float4 v = *(const float4*)(x + (size_t)i * 4);
            ushort4 o;
            o.x = f2b(v.x); o.y = f2b(v.y); o.z = f2b(v.z); o.w = f2b(v.w);
            *(ushort4*)(xb + (size_t)i * 4) = o;
            int r = 0;
            r = __builtin_amdgcn_cvt_pk_fp8_f32(v.x, v.y, r, false);
            r = __builtin_amdgcn_cvt_pk_fp8_f32(v.z, v.w, r, true);
            *(int*)(xb8 + (size_t)i * 4) = r;
        }
    } else if (b < nbc + 1024) {
        const int job = b - nbc;            // 0..1023; 512 blocks per Bt
        const int idx = (job & 511) * 256 + threadIdx.x;
        const float* Wl = (job < 512) ? W1l : W2l;
        const float* Wr = (job < 512) ? W1r : W2r;
        unsigned short* Bt = (job < 512) ? Bt1 : Bt2;
        const int n = idx >> 9;
        const int k = idx & 511;
        float v = (k < 256) ? Wl[(size_t)k * 256 + n] : Wr[(size_t)(k - 256) * 256 + n];
        Bt[idx] = f2b(v);
    } else if (b < nbc + 1024 + (N + 255) / 256) {
        const int i = (b - nbc - 1024) * 256 + threadIdx.x;
        if (i < N) cnt[i] = 0;
    } else {
        // zero-row N of xb8 and hb8 (backing store for invalid edge slots)
        const int i = threadIdx.x;
        xb8[(size_t)N * 256 + i] = 0;
        hb8[(size_t)N * 256 + i] = 0;
    }
}

// ---------------- mean aggregation (padded CSR, fp8 gather) ----------------
// KEY CHANGE: gather inputs are fp8 e4m3 -> 256B/edge (was 512B bf16),
// halving both bytes AND 16B-request count through the memory system.
// Rationale: r4 (geometry), r7 (hoisted/unconditional), r9 (forced DMA MLP)
// all left the aggregate at its ~7.5 TB/s random-gather service plateau ->
// the only remaining lever is traffic itself. GEMM path stays bf16.
// Layout: 1 node/wave; lane = 16*e4 + f reads features f*16..f*16+15 of
// edge (4u+e4): 4 edges per instruction, 8 instructions in flight (deg<=32),
// registers only (no LDS - r9's conflict/occupancy mistake reverted).
// acc[16] per lane; reduce via shfl_xor(16,32); lanes 0-15 write 32B each.
__global__ __launch_bounds__(256) void aggregate_kernel(const unsigned char* __restrict__ xb8,
                                                        const int* __restrict__ cnt,
                                                        const int* __restrict__ colp,
                                                        unsigned short* __restrict__ mean,
                                                        int N) {
    const int wave = threadIdx.x >> 6;
    const int n = blockIdx.x * 4 + wave;
    if (n >= N) return;                    // no barriers in kernel: safe
    const int lane = threadIdx.x & 63;
    const int e4 = lane >> 4;              // edge within quad (0..3)
    const int f  = lane & 15;              // feature block (16 fp8 = 16B)
    const int degT = cnt[n];
    const int degS = degT < CAP ? degT : CAP;

    int idx = N;                           // default -> fp8 zero row
    if (lane < degS) idx = colp[n * CAP + lane];
    const unsigned char* basep = xb8 + f * 16;

    const bool big = (degS > 16);          // wave-uniform

    // hoist cross-lane index gathers for edges 0..31
    int cidx[8];
#pragma unroll
    for (int u = 0; u < 8; u++) cidx[u] = __shfl(idx, u * 4 + e4);

    float acc[16];
#pragma unroll
    for (int k = 0; k < 16; k++) acc[k] = 0.f;

    // edges 0..31: 4 edges/instr, up to 8 instrs back-to-back
    int4 v[8];
#pragma unroll
    for (int u = 0; u < 4; u++) v[u] = *(const int4*)(basep + (size_t)cidx[u] * 256);
    if (big) {
#pragma unroll
        for (int u = 4; u < 8; u++) v[u] = *(const int4*)(basep + (size_t)cidx[u] * 256);
    }
    __builtin_amdgcn_sched_barrier(0);
#pragma unroll
    for (int u = 0; u < 4; u++) acc16f8(acc, v[u]);
    if (big) {
#pragma unroll
        for (int u = 4; u < 8; u++) acc16f8(acc, v[u]);
    }

    // rare tail (deg > 32): 16 edges per pass
#pragma unroll 1
    for (int base = 32; base < degS; base += 16) {
        int cw[4];
#pragma unroll
        for (int u = 0; u < 4; u++) cw[u] = __shfl(idx, base + u * 4 + e4);
        int4 w[4];
#pragma unroll
        for (int u = 0; u < 4; u++) w[u] = *(const int4*)(basep + (size_t)cw[u] * 256);
        __builtin_amdgcn_sched_barrier(0);
#pragma unroll
        for (int u = 0; u < 4; u++) acc16f8(acc, w[u]);
    }

    // reduce across the 4 edge-groups
#pragma unroll
    for (int k = 0; k < 16; k++) {
        acc[k] += __shfl_xor(acc[k], 16);
        acc[k] += __shfl_xor(acc[k], 32);
    }

    if (lane < 16) {                       // lane covers features lane*16..+15
        const float inv = 1.0f / (float)(degT > 0 ? degT : 1);
        union { unsigned short us[16]; int4 q[2]; } o;
#pragma unroll
        for (int k = 0; k < 16; k++) o.us[k] = f2b(acc[k] * inv);
        *(int4*)(mean + (size_t)n * 256 + lane * 16) = o.q[0];
        *(int4*)(mean + (size_t)n * 256 + lane * 16 + 8) = o.q[1];
    }
}

// ---------------- fused GEMM: C = [A0 | A1] @ Bt^T + bias ----------------
// 128x128 tile, BK=64, 2-deep counted-vmcnt pipeline, 8-seg XOR swizzle
// (conflicts==0), setprio around MFMA cluster, LDS-repacked epilogue.
// CHANGE: RELU variant additionally emits fp8 copy (hb8) for layer-2 gather.
template <int RELU>
__global__ __launch_bounds__(256) void gemm_kernel(const unsigned short* __restrict__ A0,
                                                   const unsigned short* __restrict__ A1,
                                                   const unsigned short* __restrict__ Bt,
                                                   const float* __restrict__ bias,
                                                   float* __restrict__ outF,
                                                   unsigned short* __restrict__ outB,
                                                   unsigned char* __restrict__ outB8,
                                                   int M) {
    __shared__ unsigned short smem[4][128 * 64];   // [0..1]=A bufs, [2..3]=B bufs
    const int tid = threadIdx.x;
    const int m0 = blockIdx.x * 128;
    const int n0 = blockIdx.y * 128;
    const int wave = tid >> 6, lane = tid & 63;
    const int wm = (wave >> 1) * 64, wn = (wave & 1) * 64;
    const int lr = lane & 15, lg = lane >> 4;

    const int r8 = lane >> 3;                       // row-within-8
    const int koffs = ((lane & 7) ^ r8) * 8;        // pre-swizzled k-offset (shorts)
    int arow[4], brow[4];
#pragma unroll
    for (int q = 0; q < 4; q++) {
        int r = m0 + (wave * 4 + q) * 8 + r8;
        arow[q] = (r < M) ? r : (M - 1);
        brow[q] = n0 + (wave * 4 + q) * 8 + r8;
    }

    f32x4 acc[4][4];
#pragma unroll
    for (int i = 0; i < 4; i++)
#pragma unroll
        for (int j = 0; j < 4; j++) acc[i][j] = (f32x4)0.0f;

    auto stage = [&](int buf, int kt) {
        const int k0 = kt * 64;
        const unsigned short* Asrc = (k0 < 256) ? A0 : A1;
        const int kk = k0 & 255;
        char* asb = (char*)(&smem[buf][0]);
        char* bsb = (char*)(&smem[2 + buf][0]);
#pragma unroll
        for (int q = 0; q < 4; q++)
            __builtin_amdgcn_global_load_lds(
                (const __attribute__((address_space(1))) void*)(Asrc + (size_t)arow[q] * 256 + kk + koffs),
                (__attribute__((address_space(3))) void*)(asb + (wave * 4 + q) * 1024), 16, 0, 0);
#pragma unroll
        for (int q = 0; q < 4; q++)
            __builtin_amdgcn_global_load_lds(
                (const __attribute__((address_space(1))) void*)(Bt + (size_t)brow[q] * 512 + k0 + koffs),
                (__attribute__((address_space(3))) void*)(bsb + (wave * 4 + q) * 1024), 16, 0, 0);
    };

    stage(0, 0);
    stage(1, 1);

#pragma unroll 1
    for (int t = 0; t < 8; t++) {
        if (t < 7) asm volatile("s_waitcnt vmcnt(8)" ::: "memory");
        else       asm volatile("s_waitcnt vmcnt(0)" ::: "memory");
        __builtin_amdgcn_s_barrier();          // all waves' tile-t loads landed
        asm volatile("" ::: "memory");
        __builtin_amdgcn_sched_barrier(0);

        const int cur = t & 1;
        s16x8 a[2][4], b[2][4];
#pragma unroll
        for (int ks = 0; ks < 2; ks++)
#pragma unroll
            for (int i = 0; i < 4; i++) {
                const int row = wm + i * 16 + lr;
                const int u = (ks * 4 + lg) ^ (lr & 7);
                a[ks][i] = *(const s16x8*)(&smem[cur][row * 64 + u * 8]);
            }
#pragma unroll
        for (int ks = 0; ks < 2; ks++)
#pragma unroll
            for (int j = 0; j < 4; j++) {
                const int row = wn + j * 16 + lr;
                const int u = (ks * 4 + lg) ^ (lr & 7);
                b[ks][j] = *(const s16x8*)(&smem[2 + cur][row * 64 + u * 8]);
            }

        asm volatile("s_waitcnt lgkmcnt(0)" ::: "memory");
        __builtin_amdgcn_sched_barrier(0);
        __builtin_amdgcn_s_barrier();          // all waves done reading buf[cur]
        asm volatile("" ::: "memory");
        __builtin_amdgcn_sched_barrier(0);

        if (t < 6) stage(cur, t + 2);          // refill freed buffer behind MFMA

        __builtin_amdgcn_s_setprio(1);
#pragma unroll
        for (int ks = 0; ks < 2; ks++)
#pragma unroll
            for (int i = 0; i < 4; i++)
#pragma unroll
                for (int j = 0; j < 4; j++)
                    acc[i][j] = __builtin_amdgcn_mfma_f32_16x16x32_bf16(a[ks][i], b[ks][j], acc[i][j], 0, 0, 0);
        __builtin_amdgcn_s_setprio(0);
    }

    // ---- epilogue: per-wave LDS repack -> coalesced stores ----
    float* wbase = ((float*)&smem[0][0]) + wave * 2304;
#pragma unroll
    for (int hf = 0; hf < 2; hf++) {
#pragma unroll
        for (int j2 = 0; j2 < 2; j2++) {
            const int j = hf * 2 + j2;
            const int n = n0 + wn + j * 16 + lr;
            const float bv = bias[n];
#pragma unroll
            for (int i = 0; i < 4; i++)
#pragma unroll
                for (int r = 0; r < 4; r++) {
                    const int row = i * 16 + lg * 4 + r;
                    float v = acc[i][j][r] + bv;
                    if (RELU) v = fmaxf(v, 0.0f);
                    wbase[row * 36 + j2 * 16 + lr] = v;
                }
        }
        asm volatile("s_waitcnt lgkmcnt(0)" ::: "memory");
        __builtin_amdgcn_sched_barrier(0);
        if (RELU) {
#pragma unroll
            for (int c = 0; c < 4; c++) {
                const int row = (lane >> 2) + 16 * c;
                const int col8 = (lane & 3) * 8;
                const int gm = m0 + wm + row;
                const int ncol = n0 + wn + hf * 32 + col8;
                f32x4 t0 = *(f32x4*)(wbase + row * 36 + col8);
                f32x4 t1 = *(f32x4*)(wbase + row * 36 + col8 + 4);
                union { unsigned short us[8]; int4 v; } o;
#pragma unroll
                for (int q = 0; q < 4; q++) { o.us[q] = f2b(t0[q]); o.us[4 + q] = f2b(t1[q]); }
                int r0 = 0, r1 = 0;
                r0 = __builtin_amdgcn_cvt_pk_fp8_f32(t0[0], t0[1], r0, false);
                r0 = __builtin_amdgcn_cvt_pk_fp8_f32(t0[2], t0[3], r0, true);
                r1 = __builtin_amdgcn_cvt_pk_fp8_f32(t1[0], t1[1], r1, false);
                r1 = __builtin_amdgcn_cvt_pk_fp8_f32(t1[2], t1[3], r1, true);
                if (gm < M) {
                    *(int4*)(outB + (size_t)gm * 256 + ncol) = o.v;
                    int2 p; p.x = r0; p.y = r1;
                    *(int2*)(outB8 + (size_t)gm * 256 + ncol) = p;
                }
            }
        } else {
#pragma unroll
            for (int c = 0; c < 8; c++) {
                const int row = (lane >> 3) + 8 * c;
                const int col4 = (lane & 7) * 4;
                const int gm = m0 + wm + row;
                f32x4 t = *(f32x4*)(wbase + row * 36 + col4);
                if (gm < M)
                    *(f32x4*)(outF + (size_t)gm * 256 + n0 + wn + hf * 32 + col4) = t;
            }
        }
        asm volatile("s_waitcnt lgkmcnt(0)" ::: "memory");
        __builtin_amdgcn_sched_barrier(0);
    }
}

extern "C" void kernel_launch(void* const* d_in, const int* in_sizes, int n_in,
                              void* d_out, int out_size, void* d_ws, size_t ws_size,
                              hipStream_t stream) {
    const float* x   = (const float*)d_in[0];
    const int*   ei  = (const int*)d_in[1];
    const float* W1l = (const float*)d_in[2];
    const float* b1  = (const float*)d_in[3];
    const float* W1r = (const float*)d_in[4];
    const float* W2l = (const float*)d_in[5];
    const float* b2  = (const float*)d_in[6];
    const float* W2r = (const float*)d_in[7];
    float* out = (float*)d_out;

    const int N = in_sizes[0] / 256;   // 50000
    const int E = in_sizes[1] / 2;     // 800000
    const int* src = ei;
    const int* dst = ei + E;

    char* ws = (char*)d_ws;
    size_t off = 0;
    auto alloc = [&](size_t bytes) -> void* {
        void* p = ws + off;
        off += (bytes + 255) & ~(size_t)255;
        return p;
    };
    int* cnt  = (int*)alloc((size_t)N * 4);
    int* colp = (int*)alloc((size_t)N * CAP * 4);
    unsigned short* xb  = (unsigned short*)alloc((size_t)N * 256 * 2);
    unsigned short* hb  = (unsigned short*)alloc((size_t)N * 256 * 2);
    unsigned short* mb  = (unsigned short*)alloc((size_t)N * 256 * 2);
    unsigned char*  xb8 = (unsigned char*)alloc((size_t)(N + 1) * 256);   // +zero row
    unsigned char*  hb8 = (unsigned char*)alloc((size_t)(N + 1) * 256);   // +zero row
    unsigned short* Bt1 = (unsigned short*)alloc((size_t)256 * 512 * 2);
    unsigned short* Bt2 = (unsigned short*)alloc((size_t)256 * 512 * 2);

    // merged prep: x->bf16 + x->fp8 + Bt builds + cnt zeroing + fp8 zero-rows
    const int n4 = N * 256 / 4;
    const int nbc = (n4 + 255) / 256;
    const int nzb = (N + 255) / 256;
    prep_kernel<<<nbc + 1024 + nzb + 1, 256, 0, stream>>>(x, xb, xb8, n4, nbc,
                                                          W1l, W1r, Bt1, W2l, W2r, Bt2,
                                                          cnt, N, hb8);

    // padded-CSR build: one atomic pass (after cnt zeroed by prep)
    build_kernel<<<(E + 1023) / 1024, 256, 0, stream>>>(src, dst, E, cnt, colp);

    const int mtiles = (N + 127) / 128;
    dim3 ggrid(mtiles, 2);
    const int ablocks = (N + 3) / 4;

    // layer 1: mean(x) -> mb; h = relu([mb|xb] @ Bt1 + b1) -> hb (bf16) + hb8 (fp8)
    aggregate_kernel<<<ablocks, 256, 0, stream>>>(xb8, cnt, colp, mb, N);
    gemm_kernel<1><<<ggrid, 256, 0, stream>>>(mb, xb, Bt1, b1, nullptr, hb, hb8, N);

    // layer 2: mean(h) -> mb; out = [mb|hb] @ Bt2 + b2 (fp32)
    aggregate_kernel<<<ablocks, 256, 0, stream>>>(hb8, cnt, colp, mb, N);
    gemm_kernel<0><<<ggrid, 256, 0, stream>>>(mb, hb, Bt2, b2, out, nullptr, nullptr, N);
}

// Round 11
// 279.378 us; speedup vs baseline: 1.2758x; 1.0147x over previous
//
#include <hip/hip_runtime.h>
#include <hip/hip_bf16.h>
#include <cstdint>
#include <cstddef>

typedef __attribute__((ext_vector_type(8))) short s16x8;
typedef __attribute__((ext_vector_type(4))) float f32x4;
typedef __attribute__((ext_vector_type(2))) float f32x2;

#define CAP 64   // padded-CSR slots/node; P(Poisson(16) >= 64) ~ 1e-19

static __device__ __forceinline__ float u2f(unsigned int u) {
    union { unsigned int i; float f; } c; c.i = u; return c.f;
}
static __device__ __forceinline__ unsigned short f2b(float f) {
    union { float f; unsigned int i; } c; c.f = f;
    unsigned int x = c.i;
    x += 0x7fffu + ((x >> 16) & 1u);   // round-to-nearest-even
    return (unsigned short)(x >> 16);
}

// unpack one 16B fp8x16 chunk (e4m3) and accumulate into 16 fp32 features
static __device__ __forceinline__ void acc16f8(float* acc, const int4& t) {
    f32x2 p;
    p = __builtin_amdgcn_cvt_pk_f32_fp8(t.x, false); acc[0]  += p.x; acc[1]  += p.y;
    p = __builtin_amdgcn_cvt_pk_f32_fp8(t.x, true);  acc[2]  += p.x; acc[3]  += p.y;
    p = __builtin_amdgcn_cvt_pk_f32_fp8(t.y, false); acc[4]  += p.x; acc[5]  += p.y;
    p = __builtin_amdgcn_cvt_pk_f32_fp8(t.y, true);  acc[6]  += p.x; acc[7]  += p.y;
    p = __builtin_amdgcn_cvt_pk_f32_fp8(t.z, false); acc[8]  += p.x; acc[9]  += p.y;
    p = __builtin_amdgcn_cvt_pk_f32_fp8(t.z, true);  acc[10] += p.x; acc[11] += p.y;
    p = __builtin_amdgcn_cvt_pk_f32_fp8(t.w, false); acc[12] += p.x; acc[13] += p.y;
    p = __builtin_amdgcn_cvt_pk_f32_fp8(t.w, true);  acc[14] += p.x; acc[15] += p.y;
}

// ---- merged prep: CSR edge-pass + x->bf16 + x->fp8 + Bt builds + zero-rows ----
// KEY CHANGE (r11): the padded-CSR build (800k random atomics + 4B scatters,
// ~50us standalone at VALUBusy 0.5% / 27% occupancy - pure latency+sector-
// amplified-write waiting) is merged into prep as its FIRST block range.
// build needs only ei; the convert/Bt blocks need only x/W -> independent.
// Dispatching the latency-bound edge blocks first lets them co-reside with
// the BW-bound convert blocks (latency hides under BW work, m114-style).
// cnt zeroing moved back to hipMemsetAsync (stream-ordered before prep).
// Per-edge semantics identical -> identical colp/cnt -> bit-identical output.
__global__ __launch_bounds__(256) void prep_kernel(const int* __restrict__ src,
                                                   const int* __restrict__ dst,
                                                   int E, int nbe,
                                                   int* __restrict__ cnt,
                                                   int* __restrict__ colp,
                                                   const float* __restrict__ x,
                                                   unsigned short* __restrict__ xb,
                                                   unsigned char* __restrict__ xb8,
                                                   int n4, int nbc,
                                                   const float* __restrict__ W1l, const float* __restrict__ W1r,
                                                   unsigned short* __restrict__ Bt1,
                                                   const float* __restrict__ W2l, const float* __restrict__ W2r,
                                                   unsigned short* __restrict__ Bt2,
                                                   int N,
                                                   unsigned char* __restrict__ hb8) {
    const int b = blockIdx.x;
    if (b < nbe) {
        // ---- padded-CSR edge pass (one atomic per edge) ----
        const int base = b * 1024 + threadIdx.x;
        int d[4], s[4];
        bool ok[4];
#pragma unroll
        for (int k = 0; k < 4; k++) {
            const int i = base + k * 256;
            ok[k] = (i < E);
            d[k] = ok[k] ? dst[i] : 0;
            s[k] = ok[k] ? src[i] : 0;
        }
        int p[4];
#pragma unroll
        for (int k = 0; k < 4; k++)
            if (ok[k]) p[k] = atomicAdd(&cnt[d[k]], 1);
#pragma unroll
        for (int k = 0; k < 4; k++)
            if (ok[k] && p[k] < CAP) colp[d[k] * CAP + p[k]] = s[k];
    } else if (b < nbe + nbc) {
        const int i = (b - nbe) * 256 + threadIdx.x;
        if (i < n4) {
            float4 v = *(const float4*)(x + (size_t)i * 4);
            ushort4 o;
            o.x = f2b(v.x); o.y = f2b(v.y); o.z = f2b(v.z); o.w = f2b(v.w);
            *(ushort4*)(xb + (size_t)i * 4) = o;
            int r = 0;
            r = __builtin_amdgcn_cvt_pk_fp8_f32(v.x, v.y, r, false);
            r = __builtin_amdgcn_cvt_pk_fp8_f32(v.z, v.w, r, true);
            *(int*)(xb8 + (size_t)i * 4) = r;
        }
    } else if (b < nbe + nbc + 1024) {
        const int job = b - nbe - nbc;      // 0..1023; 512 blocks per Bt
        const int idx = (job & 511) * 256 + threadIdx.x;
        const float* Wl = (job < 512) ? W1l : W2l;
        const float* Wr = (job < 512) ? W1r : W2r;
        unsigned short* Bt = (job < 512) ? Bt1 : Bt2;
        const int n = idx >> 9;
        const int k = idx & 511;
        float v = (k < 256) ? Wl[(size_t)k * 256 + n] : Wr[(size_t)(k - 256) * 256 + n];
        Bt[idx] = f2b(v);
    } else {
        // zero-row N of xb8 and hb8 (backing store for invalid edge slots)
        const int i = threadIdx.x;
        xb8[(size_t)N * 256 + i] = 0;
        hb8[(size_t)N * 256 + i] = 0;
    }
}

// ---------------- mean aggregation (padded CSR, fp8 gather; unchanged r10) -----
// fp8 e4m3 gather inputs: 256B/edge. 1 node/wave; lane = 16*e4 + f; 4 edges
// per instruction, up to 8 instrs in flight; registers only. acc[16]/lane,
// shfl_xor(16,32) reduce, lanes 0-15 write 32B each.
__global__ __launch_bounds__(256) void aggregate_kernel(const unsigned char* __restrict__ xb8,
                                                        const int* __restrict__ cnt,
                                                        const int* __restrict__ colp,
                                                        unsigned short* __restrict__ mean,
                                                        int N) {
    const int wave = threadIdx.x >> 6;
    const int n = blockIdx.x * 4 + wave;
    if (n >= N) return;                    // no barriers in kernel: safe
    const int lane = threadIdx.x & 63;
    const int e4 = lane >> 4;              // edge within quad (0..3)
    const int f  = lane & 15;              // feature block (16 fp8 = 16B)
    const int degT = cnt[n];
    const int degS = degT < CAP ? degT : CAP;

    int idx = N;                           // default -> fp8 zero row
    if (lane < degS) idx = colp[n * CAP + lane];
    const unsigned char* basep = xb8 + f * 16;

    const bool big = (degS > 16);          // wave-uniform

    // hoist cross-lane index gathers for edges 0..31
    int cidx[8];
#pragma unroll
    for (int u = 0; u < 8; u++) cidx[u] = __shfl(idx, u * 4 + e4);

    float acc[16];
#pragma unroll
    for (int k = 0; k < 16; k++) acc[k] = 0.f;

    // edges 0..31: 4 edges/instr, up to 8 instrs back-to-back
    int4 v[8];
#pragma unroll
    for (int u = 0; u < 4; u++) v[u] = *(const int4*)(basep + (size_t)cidx[u] * 256);
    if (big) {
#pragma unroll
        for (int u = 4; u < 8; u++) v[u] = *(const int4*)(basep + (size_t)cidx[u] * 256);
    }
    __builtin_amdgcn_sched_barrier(0);
#pragma unroll
    for (int u = 0; u < 4; u++) acc16f8(acc, v[u]);
    if (big) {
#pragma unroll
        for (int u = 4; u < 8; u++) acc16f8(acc, v[u]);
    }

    // rare tail (deg > 32): 16 edges per pass
#pragma unroll 1
    for (int base = 32; base < degS; base += 16) {
        int cw[4];
#pragma unroll
        for (int u = 0; u < 4; u++) cw[u] = __shfl(idx, base + u * 4 + e4);
        int4 w[4];
#pragma unroll
        for (int u = 0; u < 4; u++) w[u] = *(const int4*)(basep + (size_t)cw[u] * 256);
        __builtin_amdgcn_sched_barrier(0);
#pragma unroll
        for (int u = 0; u < 4; u++) acc16f8(acc, w[u]);
    }

    // reduce across the 4 edge-groups
#pragma unroll
    for (int k = 0; k < 16; k++) {
        acc[k] += __shfl_xor(acc[k], 16);
        acc[k] += __shfl_xor(acc[k], 32);
    }

    if (lane < 16) {                       // lane covers features lane*16..+15
        const float inv = 1.0f / (float)(degT > 0 ? degT : 1);
        union { unsigned short us[16]; int4 q[2]; } o;
#pragma unroll
        for (int k = 0; k < 16; k++) o.us[k] = f2b(acc[k] * inv);
        *(int4*)(mean + (size_t)n * 256 + lane * 16) = o.q[0];
        *(int4*)(mean + (size_t)n * 256 + lane * 16 + 8) = o.q[1];
    }
}

// ---------------- fused GEMM: C = [A0 | A1] @ Bt^T + bias (unchanged r10) ------
// 128x128 tile, BK=64, 2-deep counted-vmcnt pipeline, 8-seg XOR swizzle
// (conflicts==0), setprio around MFMA cluster, LDS-repacked epilogue.
// RELU variant additionally emits fp8 copy (hb8) for layer-2 gather.
template <int RELU>
__global__ __launch_bounds__(256) void gemm_kernel(const unsigned short* __restrict__ A0,
                                                   const unsigned short* __restrict__ A1,
                                                   const unsigned short* __restrict__ Bt,
                                                   const float* __restrict__ bias,
                                                   float* __restrict__ outF,
                                                   unsigned short* __restrict__ outB,
                                                   unsigned char* __restrict__ outB8,
                                                   int M) {
    __shared__ unsigned short smem[4][128 * 64];   // [0..1]=A bufs, [2..3]=B bufs
    const int tid = threadIdx.x;
    const int m0 = blockIdx.x * 128;
    const int n0 = blockIdx.y * 128;
    const int wave = tid >> 6, lane = tid & 63;
    const int wm = (wave >> 1) * 64, wn = (wave & 1) * 64;
    const int lr = lane & 15, lg = lane >> 4;

    const int r8 = lane >> 3;                       // row-within-8
    const int koffs = ((lane & 7) ^ r8) * 8;        // pre-swizzled k-offset (shorts)
    int arow[4], brow[4];
#pragma unroll
    for (int q = 0; q < 4; q++) {
        int r = m0 + (wave * 4 + q) * 8 + r8;
        arow[q] = (r < M) ? r : (M - 1);
        brow[q] = n0 + (wave * 4 + q) * 8 + r8;
    }

    f32x4 acc[4][4];
#pragma unroll
    for (int i = 0; i < 4; i++)
#pragma unroll
        for (int j = 0; j < 4; j++) acc[i][j] = (f32x4)0.0f;

    auto stage = [&](int buf, int kt) {
        const int k0 = kt * 64;
        const unsigned short* Asrc = (k0 < 256) ? A0 : A1;
        const int kk = k0 & 255;
        char* asb = (char*)(&smem[buf][0]);
        char* bsb = (char*)(&smem[2 + buf][0]);
#pragma unroll
        for (int q = 0; q < 4; q++)
            __builtin_amdgcn_global_load_lds(
                (const __attribute__((address_space(1))) void*)(Asrc + (size_t)arow[q] * 256 + kk + koffs),
                (__attribute__((address_space(3))) void*)(asb + (wave * 4 + q) * 1024), 16, 0, 0);
#pragma unroll
        for (int q = 0; q < 4; q++)
            __builtin_amdgcn_global_load_lds(
                (const __attribute__((address_space(1))) void*)(Bt + (size_t)brow[q] * 512 + k0 + koffs),
                (__attribute__((address_space(3))) void*)(bsb + (wave * 4 + q) * 1024), 16, 0, 0);
    };

    stage(0, 0);
    stage(1, 1);

#pragma unroll 1
    for (int t = 0; t < 8; t++) {
        if (t < 7) asm volatile("s_waitcnt vmcnt(8)" ::: "memory");
        else       asm volatile("s_waitcnt vmcnt(0)" ::: "memory");
        __builtin_amdgcn_s_barrier();          // all waves' tile-t loads landed
        asm volatile("" ::: "memory");
        __builtin_amdgcn_sched_barrier(0);

        const int cur = t & 1;
        s16x8 a[2][4], b[2][4];
#pragma unroll
        for (int ks = 0; ks < 2; ks++)
#pragma unroll
            for (int i = 0; i < 4; i++) {
                const int row = wm + i * 16 + lr;
                const int u = (ks * 4 + lg) ^ (lr & 7);
                a[ks][i] = *(const s16x8*)(&smem[cur][row * 64 + u * 8]);
            }
#pragma unroll
        for (int ks = 0; ks < 2; ks++)
#pragma unroll
            for (int j = 0; j < 4; j++) {
                const int row = wn + j * 16 + lr;
                const int u = (ks * 4 + lg) ^ (lr & 7);
                b[ks][j] = *(const s16x8*)(&smem[2 + cur][row * 64 + u * 8]);
            }

        asm volatile("s_waitcnt lgkmcnt(0)" ::: "memory");
        __builtin_amdgcn_sched_barrier(0);
        __builtin_amdgcn_s_barrier();          // all waves done reading buf[cur]
        asm volatile("" ::: "memory");
        __builtin_amdgcn_sched_barrier(0);

        if (t < 6) stage(cur, t + 2);          // refill freed buffer behind MFMA

        __builtin_amdgcn_s_setprio(1);
#pragma unroll
        for (int ks = 0; ks < 2; ks++)
#pragma unroll
            for (int i = 0; i < 4; i++)
#pragma unroll
                for (int j = 0; j < 4; j++)
                    acc[i][j] = __builtin_amdgcn_mfma_f32_16x16x32_bf16(a[ks][i], b[ks][j], acc[i][j], 0, 0, 0);
        __builtin_amdgcn_s_setprio(0);
    }

    // ---- epilogue: per-wave LDS repack -> coalesced stores ----
    float* wbase = ((float*)&smem[0][0]) + wave * 2304;
#pragma unroll
    for (int hf = 0; hf < 2; hf++) {
#pragma unroll
        for (int j2 = 0; j2 < 2; j2++) {
            const int j = hf * 2 + j2;
            const int n = n0 + wn + j * 16 + lr;
            const float bv = bias[n];
#pragma unroll
            for (int i = 0; i < 4; i++)
#pragma unroll
                for (int r = 0; r < 4; r++) {
                    const int row = i * 16 + lg * 4 + r;
                    float v = acc[i][j][r] + bv;
                    if (RELU) v = fmaxf(v, 0.0f);
                    wbase[row * 36 + j2 * 16 + lr] = v;
                }
        }
        asm volatile("s_waitcnt lgkmcnt(0)" ::: "memory");
        __builtin_amdgcn_sched_barrier(0);
        if (RELU) {
#pragma unroll
            for (int c = 0; c < 4; c++) {
                const int row = (lane >> 2) + 16 * c;
                const int col8 = (lane & 3) * 8;
                const int gm = m0 + wm + row;
                const int ncol = n0 + wn + hf * 32 + col8;
                f32x4 t0 = *(f32x4*)(wbase + row * 36 + col8);
                f32x4 t1 = *(f32x4*)(wbase + row * 36 + col8 + 4);
                union { unsigned short us[8]; int4 v; } o;
#pragma unroll
                for (int q = 0; q < 4; q++) { o.us[q] = f2b(t0[q]); o.us[4 + q] = f2b(t1[q]); }
                int r0 = 0, r1 = 0;
                r0 = __builtin_amdgcn_cvt_pk_fp8_f32(t0[0], t0[1], r0, false);
                r0 = __builtin_amdgcn_cvt_pk_fp8_f32(t0[2], t0[3], r0, true);
                r1 = __builtin_amdgcn_cvt_pk_fp8_f32(t1[0], t1[1], r1, false);
                r1 = __builtin_amdgcn_cvt_pk_fp8_f32(t1[2], t1[3], r1, true);
                if (gm < M) {
                    *(int4*)(outB + (size_t)gm * 256 + ncol) = o.v;
                    int2 p; p.x = r0; p.y = r1;
                    *(int2*)(outB8 + (size_t)gm * 256 + ncol) = p;
                }
            }
        } else {
#pragma unroll
            for (int c = 0; c < 8; c++) {
                const int row = (lane >> 3) + 8 * c;
                const int col4 = (lane & 7) * 4;
                const int gm = m0 + wm + row;
                f32x4 t = *(f32x4*)(wbase + row * 36 + col4);
                if (gm < M)
                    *(f32x4*)(outF + (size_t)gm * 256 + n0 + wn + hf * 32 + col4) = t;
            }
        }
        asm volatile("s_waitcnt lgkmcnt(0)" ::: "memory");
        __builtin_amdgcn_sched_barrier(0);
    }
}

extern "C" void kernel_launch(void* const* d_in, const int* in_sizes, int n_in,
                              void* d_out, int out_size, void* d_ws, size_t ws_size,
                              hipStream_t stream) {
    const float* x   = (const float*)d_in[0];
    const int*   ei  = (const int*)d_in[1];
    const float* W1l = (const float*)d_in[2];
    const float* b1  = (const float*)d_in[3];
    const float* W1r = (const float*)d_in[4];
    const float* W2l = (const float*)d_in[5];
    const float* b2  = (const float*)d_in[6];
    const float* W2r = (const float*)d_in[7];
    float* out = (float*)d_out;

    const int N = in_sizes[0] / 256;   // 50000
    const int E = in_sizes[1] / 2;     // 800000
    const int* src = ei;
    const int* dst = ei + E;

    char* ws = (char*)d_ws;
    size_t off = 0;
    auto alloc = [&](size_t bytes) -> void* {
        void* p = ws + off;
        off += (bytes + 255) & ~(size_t)255;
        return p;
    };
    int* cnt  = (int*)alloc((size_t)N * 4);
    int* colp = (int*)alloc((size_t)N * CAP * 4);
    unsigned short* xb  = (unsigned short*)alloc((size_t)N * 256 * 2);
    unsigned short* hb  = (unsigned short*)alloc((size_t)N * 256 * 2);
    unsigned short* mb  = (unsigned short*)alloc((size_t)N * 256 * 2);
    unsigned char*  xb8 = (unsigned char*)alloc((size_t)(N + 1) * 256);   // +zero row
    unsigned char*  hb8 = (unsigned char*)alloc((size_t)(N + 1) * 256);   // +zero row
    unsigned short* Bt1 = (unsigned short*)alloc((size_t)256 * 512 * 2);
    unsigned short* Bt2 = (unsigned short*)alloc((size_t)256 * 512 * 2);

    // cnt zeroing: stream-ordered memset BEFORE the merged prep (no intra-
    // kernel ordering needed between zeroing and the edge pass)
    hipMemsetAsync(cnt, 0, (size_t)N * 4, stream);

    // merged prep: edge-pass first (latency-bound, co-resides with BW blocks)
    const int n4 = N * 256 / 4;
    const int nbc = (n4 + 255) / 256;
    const int nbe = (E + 1023) / 1024;
    prep_kernel<<<nbe + nbc + 1024 + 1, 256, 0, stream>>>(src, dst, E, nbe, cnt, colp,
                                                          x, xb, xb8, n4, nbc,
                                                          W1l, W1r, Bt1, W2l, W2r, Bt2,
                                                          N, hb8);

    const int mtiles = (N + 127) / 128;
    dim3 ggrid(mtiles, 2);
    const int ablocks = (N + 3) / 4;

    // layer 1: mean(x) -> mb; h = relu([mb|xb] @ Bt1 + b1) -> hb (bf16) + hb8 (fp8)
    aggregate_kernel<<<ablocks, 256, 0, stream>>>(xb8, cnt, colp, mb, N);
    gemm_kernel<1><<<ggrid, 256, 0, stream>>>(mb, xb, Bt1, b1, nullptr, hb, hb8, N);

    // layer 2: mean(h) -> mb; out = [mb|hb] @ Bt2 + b2 (fp32)
    aggregate_kernel<<<ablocks, 256, 0, stream>>>(hb8, cnt, colp, mb, N);
    gemm_kernel<0><<<ggrid, 256, 0, stream>>>(mb, hb, Bt2, b2, out, nullptr, nullptr, N);
}

// Round 12
// 278.432 us; speedup vs baseline: 1.2802x; 1.0034x over previous
//
#include <hip/hip_runtime.h>
#include <hip/hip_bf16.h>
#include <cstdint>
#include <cstddef>

typedef __attribute__((ext_vector_type(8))) short s16x8;
typedef __attribute__((ext_vector_type(4))) float f32x4;
typedef __attribute__((ext_vector_type(2))) float f32x2;

#define CAP 64   // padded-CSR slots/node; P(Poisson(16) >= 64) ~ 1e-19

static __device__ __forceinline__ float u2f(unsigned int u) {
    union { unsigned int i; float f; } c; c.i = u; return c.f;
}
static __device__ __forceinline__ unsigned short f2b(float f) {
    union { float f; unsigned int i; } c; c.f = f;
    unsigned int x = c.i;
    x += 0x7fffu + ((x >> 16) & 1u);   // round-to-nearest-even
    return (unsigned short)(x >> 16);
}

// unpack one 16B fp8x16 chunk (e4m3) and accumulate into 16 fp32 features
static __device__ __forceinline__ void acc16f8(float* acc, const int4& t) {
    f32x2 p;
    p = __builtin_amdgcn_cvt_pk_f32_fp8(t.x, false); acc[0]  += p.x; acc[1]  += p.y;
    p = __builtin_amdgcn_cvt_pk_f32_fp8(t.x, true);  acc[2]  += p.x; acc[3]  += p.y;
    p = __builtin_amdgcn_cvt_pk_f32_fp8(t.y, false); acc[4]  += p.x; acc[5]  += p.y;
    p = __builtin_amdgcn_cvt_pk_f32_fp8(t.y, true);  acc[6]  += p.x; acc[7]  += p.y;
    p = __builtin_amdgcn_cvt_pk_f32_fp8(t.z, false); acc[8]  += p.x; acc[9]  += p.y;
    p = __builtin_amdgcn_cvt_pk_f32_fp8(t.z, true);  acc[10] += p.x; acc[11] += p.y;
    p = __builtin_amdgcn_cvt_pk_f32_fp8(t.w, false); acc[12] += p.x; acc[13] += p.y;
    p = __builtin_amdgcn_cvt_pk_f32_fp8(t.w, true);  acc[14] += p.x; acc[15] += p.y;
}

// ---- merged prep: CSR edge-pass + x->bf16 + x->fp8 + Bt builds + zero-rows ----
// r12 KEY CHANGE: colp is uint16 (src < 50000 < 65536). Footprint 12.8->6.4MB;
// per-XCD dirty scatter set ~3.2MB < 4MB L2 -> dirty sectors survive to a
// single writeback instead of eviction churn (r11: WRITE_SIZE 86.5MB vs
// ~43MB useful at VALUBusy 2.9% - the scatter churn IS the kernel's time).
// Stored/loaded index values identical -> bit-identical output.
__global__ __launch_bounds__(256) void prep_kernel(const int* __restrict__ src,
                                                   const int* __restrict__ dst,
                                                   int E, int nbe,
                                                   int* __restrict__ cnt,
                                                   unsigned short* __restrict__ colp,
                                                   const float* __restrict__ x,
                                                   unsigned short* __restrict__ xb,
                                                   unsigned char* __restrict__ xb8,
                                                   int n4, int nbc,
                                                   const float* __restrict__ W1l, const float* __restrict__ W1r,
                                                   unsigned short* __restrict__ Bt1,
                                                   const float* __restrict__ W2l, const float* __restrict__ W2r,
                                                   unsigned short* __restrict__ Bt2,
                                                   int N,
                                                   unsigned char* __restrict__ hb8) {
    const int b = blockIdx.x;
    if (b < nbe) {
        // ---- padded-CSR edge pass (one atomic per edge) ----
        const int base = b * 1024 + threadIdx.x;
        int d[4], s[4];
        bool ok[4];
#pragma unroll
        for (int k = 0; k < 4; k++) {
            const int i = base + k * 256;
            ok[k] = (i < E);
            d[k] = ok[k] ? dst[i] : 0;
            s[k] = ok[k] ? src[i] : 0;
        }
        int p[4];
#pragma unroll
        for (int k = 0; k < 4; k++)
            if (ok[k]) p[k] = atomicAdd(&cnt[d[k]], 1);
#pragma unroll
        for (int k = 0; k < 4; k++)
            if (ok[k] && p[k] < CAP) colp[d[k] * CAP + p[k]] = (unsigned short)s[k];
    } else if (b < nbe + nbc) {
        const int i = (b - nbe) * 256 + threadIdx.x;
        if (i < n4) {
            float4 v = *(const float4*)(x + (size_t)i * 4);
            ushort4 o;
            o.x = f2b(v.x); o.y = f2b(v.y); o.z = f2b(v.z); o.w = f2b(v.w);
            *(ushort4*)(xb + (size_t)i * 4) = o;
            int r = 0;
            r = __builtin_amdgcn_cvt_pk_fp8_f32(v.x, v.y, r, false);
            r = __builtin_amdgcn_cvt_pk_fp8_f32(v.z, v.w, r, true);
            *(int*)(xb8 + (size_t)i * 4) = r;
        }
    } else if (b < nbe + nbc + 1024) {
        const int job = b - nbe - nbc;      // 0..1023; 512 blocks per Bt
        const int idx = (job & 511) * 256 + threadIdx.x;
        const float* Wl = (job < 512) ? W1l : W2l;
        const float* Wr = (job < 512) ? W1r : W2r;
        unsigned short* Bt = (job < 512) ? Bt1 : Bt2;
        const int n = idx >> 9;
        const int k = idx & 511;
        float v = (k < 256) ? Wl[(size_t)k * 256 + n] : Wr[(size_t)(k - 256) * 256 + n];
        Bt[idx] = f2b(v);
    } else {
        // zero-row N of xb8 and hb8 (backing store for invalid edge slots)
        const int i = threadIdx.x;
        xb8[(size_t)N * 256 + i] = 0;
        hb8[(size_t)N * 256 + i] = 0;
    }
}

// ---------------- mean aggregation (padded CSR, fp8 gather; unchanged r10) -----
// fp8 e4m3 gather inputs: 256B/edge. 1 node/wave; lane = 16*e4 + f; 4 edges
// per instruction, up to 8 instrs in flight; registers only. acc[16]/lane,
// shfl_xor(16,32) reduce, lanes 0-15 write 32B each. colp now uint16
// (same values; one coalesced 128B read per wave).
__global__ __launch_bounds__(256) void aggregate_kernel(const unsigned char* __restrict__ xb8,
                                                        const int* __restrict__ cnt,
                                                        const unsigned short* __restrict__ colp,
                                                        unsigned short* __restrict__ mean,
                                                        int N) {
    const int wave = threadIdx.x >> 6;
    const int n = blockIdx.x * 4 + wave;
    if (n >= N) return;                    // no barriers in kernel: safe
    const int lane = threadIdx.x & 63;
    const int e4 = lane >> 4;              // edge within quad (0..3)
    const int f  = lane & 15;              // feature block (16 fp8 = 16B)
    const int degT = cnt[n];
    const int degS = degT < CAP ? degT : CAP;

    int idx = N;                           // default -> fp8 zero row
    if (lane < degS) idx = (int)colp[n * CAP + lane];
    const unsigned char* basep = xb8 + f * 16;

    const bool big = (degS > 16);          // wave-uniform

    // hoist cross-lane index gathers for edges 0..31
    int cidx[8];
#pragma unroll
    for (int u = 0; u < 8; u++) cidx[u] = __shfl(idx, u * 4 + e4);

    float acc[16];
#pragma unroll
    for (int k = 0; k < 16; k++) acc[k] = 0.f;

    // edges 0..31: 4 edges/instr, up to 8 instrs back-to-back
    int4 v[8];
#pragma unroll
    for (int u = 0; u < 4; u++) v[u] = *(const int4*)(basep + (size_t)cidx[u] * 256);
    if (big) {
#pragma unroll
        for (int u = 4; u < 8; u++) v[u] = *(const int4*)(basep + (size_t)cidx[u] * 256);
    }
    __builtin_amdgcn_sched_barrier(0);
#pragma unroll
    for (int u = 0; u < 4; u++) acc16f8(acc, v[u]);
    if (big) {
#pragma unroll
        for (int u = 4; u < 8; u++) acc16f8(acc, v[u]);
    }

    // rare tail (deg > 32): 16 edges per pass
#pragma unroll 1
    for (int base = 32; base < degS; base += 16) {
        int cw[4];
#pragma unroll
        for (int u = 0; u < 4; u++) cw[u] = __shfl(idx, base + u * 4 + e4);
        int4 w[4];
#pragma unroll
        for (int u = 0; u < 4; u++) w[u] = *(const int4*)(basep + (size_t)cw[u] * 256);
        __builtin_amdgcn_sched_barrier(0);
#pragma unroll
        for (int u = 0; u < 4; u++) acc16f8(acc, w[u]);
    }

    // reduce across the 4 edge-groups
#pragma unroll
    for (int k = 0; k < 16; k++) {
        acc[k] += __shfl_xor(acc[k], 16);
        acc[k] += __shfl_xor(acc[k], 32);
    }

    if (lane < 16) {                       // lane covers features lane*16..+15
        const float inv = 1.0f / (float)(degT > 0 ? degT : 1);
        union { unsigned short us[16]; int4 q[2]; } o;
#pragma unroll
        for (int k = 0; k < 16; k++) o.us[k] = f2b(acc[k] * inv);
        *(int4*)(mean + (size_t)n * 256 + lane * 16) = o.q[0];
        *(int4*)(mean + (size_t)n * 256 + lane * 16 + 8) = o.q[1];
    }
}

// ---------------- fused GEMM: C = [A0 | A1] @ Bt^T + bias (unchanged r10) ------
// 128x128 tile, BK=64, 2-deep counted-vmcnt pipeline, 8-seg XOR swizzle
// (conflicts==0), setprio around MFMA cluster, LDS-repacked epilogue.
// RELU variant additionally emits fp8 copy (hb8) for layer-2 gather.
template <int RELU>
__global__ __launch_bounds__(256) void gemm_kernel(const unsigned short* __restrict__ A0,
                                                   const unsigned short* __restrict__ A1,
                                                   const unsigned short* __restrict__ Bt,
                                                   const float* __restrict__ bias,
                                                   float* __restrict__ outF,
                                                   unsigned short* __restrict__ outB,
                                                   unsigned char* __restrict__ outB8,
                                                   int M) {
    __shared__ unsigned short smem[4][128 * 64];   // [0..1]=A bufs, [2..3]=B bufs
    const int tid = threadIdx.x;
    const int m0 = blockIdx.x * 128;
    const int n0 = blockIdx.y * 128;
    const int wave = tid >> 6, lane = tid & 63;
    const int wm = (wave >> 1) * 64, wn = (wave & 1) * 64;
    const int lr = lane & 15, lg = lane >> 4;

    const int r8 = lane >> 3;                       // row-within-8
    const int koffs = ((lane & 7) ^ r8) * 8;        // pre-swizzled k-offset (shorts)
    int arow[4], brow[4];
#pragma unroll
    for (int q = 0; q < 4; q++) {
        int r = m0 + (wave * 4 + q) * 8 + r8;
        arow[q] = (r < M) ? r : (M - 1);
        brow[q] = n0 + (wave * 4 + q) * 8 + r8;
    }

    f32x4 acc[4][4];
#pragma unroll
    for (int i = 0; i < 4; i++)
#pragma unroll
        for (int j = 0; j < 4; j++) acc[i][j] = (f32x4)0.0f;

    auto stage = [&](int buf, int kt) {
        const int k0 = kt * 64;
        const unsigned short* Asrc = (k0 < 256) ? A0 : A1;
        const int kk = k0 & 255;
        char* asb = (char*)(&smem[buf][0]);
        char* bsb = (char*)(&smem[2 + buf][0]);
#pragma unroll
        for (int q = 0; q < 4; q++)
            __builtin_amdgcn_global_load_lds(
                (const __attribute__((address_space(1))) void*)(Asrc + (size_t)arow[q] * 256 + kk + koffs),
                (__attribute__((address_space(3))) void*)(asb + (wave * 4 + q) * 1024), 16, 0, 0);
#pragma unroll
        for (int q = 0; q < 4; q++)
            __builtin_amdgcn_global_load_lds(
                (const __attribute__((address_space(1))) void*)(Bt + (size_t)brow[q] * 512 + k0 + koffs),
                (__attribute__((address_space(3))) void*)(bsb + (wave * 4 + q) * 1024), 16, 0, 0);
    };

    stage(0, 0);
    stage(1, 1);

#pragma unroll 1
    for (int t = 0; t < 8; t++) {
        if (t < 7) asm volatile("s_waitcnt vmcnt(8)" ::: "memory");
        else       asm volatile("s_waitcnt vmcnt(0)" ::: "memory");
        __builtin_amdgcn_s_barrier();          // all waves' tile-t loads landed
        asm volatile("" ::: "memory");
        __builtin_amdgcn_sched_barrier(0);

        const int cur = t & 1;
        s16x8 a[2][4], b[2][4];
#pragma unroll
        for (int ks = 0; ks < 2; ks++)
#pragma unroll
            for (int i = 0; i < 4; i++) {
                const int row = wm + i * 16 + lr;
                const int u = (ks * 4 + lg) ^ (lr & 7);
                a[ks][i] = *(const s16x8*)(&smem[cur][row * 64 + u * 8]);
            }
#pragma unroll
        for (int ks = 0; ks < 2; ks++)
#pragma unroll
            for (int j = 0; j < 4; j++) {
                const int row = wn + j * 16 + lr;
                const int u = (ks * 4 + lg) ^ (lr & 7);
                b[ks][j] = *(const s16x8*)(&smem[2 + cur][row * 64 + u * 8]);
            }

        asm volatile("s_waitcnt lgkmcnt(0)" ::: "memory");
        __builtin_amdgcn_sched_barrier(0);
        __builtin_amdgcn_s_barrier();          // all waves done reading buf[cur]
        asm volatile("" ::: "memory");
        __builtin_amdgcn_sched_barrier(0);

        if (t < 6) stage(cur, t + 2);          // refill freed buffer behind MFMA

        __builtin_amdgcn_s_setprio(1);
#pragma unroll
        for (int ks = 0; ks < 2; ks++)
#pragma unroll
            for (int i = 0; i < 4; i++)
#pragma unroll
                for (int j = 0; j < 4; j++)
                    acc[i][j] = __builtin_amdgcn_mfma_f32_16x16x32_bf16(a[ks][i], b[ks][j], acc[i][j], 0, 0, 0);
        __builtin_amdgcn_s_setprio(0);
    }

    // ---- epilogue: per-wave LDS repack -> coalesced stores ----
    float* wbase = ((float*)&smem[0][0]) + wave * 2304;
#pragma unroll
    for (int hf = 0; hf < 2; hf++) {
#pragma unroll
        for (int j2 = 0; j2 < 2; j2++) {
            const int j = hf * 2 + j2;
            const int n = n0 + wn + j * 16 + lr;
            const float bv = bias[n];
#pragma unroll
            for (int i = 0; i < 4; i++)
#pragma unroll
                for (int r = 0; r < 4; r++) {
                    const int row = i * 16 + lg * 4 + r;
                    float v = acc[i][j][r] + bv;
                    if (RELU) v = fmaxf(v, 0.0f);
                    wbase[row * 36 + j2 * 16 + lr] = v;
                }
        }
        asm volatile("s_waitcnt lgkmcnt(0)" ::: "memory");
        __builtin_amdgcn_sched_barrier(0);
        if (RELU) {
#pragma unroll
            for (int c = 0; c < 4; c++) {
                const int row = (lane >> 2) + 16 * c;
                const int col8 = (lane & 3) * 8;
                const int gm = m0 + wm + row;
                const int ncol = n0 + wn + hf * 32 + col8;
                f32x4 t0 = *(f32x4*)(wbase + row * 36 + col8);
                f32x4 t1 = *(f32x4*)(wbase + row * 36 + col8 + 4);
                union { unsigned short us[8]; int4 v; } o;
#pragma unroll
                for (int q = 0; q < 4; q++) { o.us[q] = f2b(t0[q]); o.us[4 + q] = f2b(t1[q]); }
                int r0 = 0, r1 = 0;
                r0 = __builtin_amdgcn_cvt_pk_fp8_f32(t0[0], t0[1], r0, false);
                r0 = __builtin_amdgcn_cvt_pk_fp8_f32(t0[2], t0[3], r0, true);
                r1 = __builtin_amdgcn_cvt_pk_fp8_f32(t1[0], t1[1], r1, false);
                r1 = __builtin_amdgcn_cvt_pk_fp8_f32(t1[2], t1[3], r1, true);
                if (gm < M) {
                    *(int4*)(outB + (size_t)gm * 256 + ncol) = o.v;
                    int2 p; p.x = r0; p.y = r1;
                    *(int2*)(outB8 + (size_t)gm * 256 + ncol) = p;
                }
            }
        } else {
#pragma unroll
            for (int c = 0; c < 8; c++) {
                const int row = (lane >> 3) + 8 * c;
                const int col4 = (lane & 7) * 4;
                const int gm = m0 + wm + row;
                f32x4 t = *(f32x4*)(wbase + row * 36 + col4);
                if (gm < M)
                    *(f32x4*)(outF + (size_t)gm * 256 + n0 + wn + hf * 32 + col4) = t;
            }
        }
        asm volatile("s_waitcnt lgkmcnt(0)" ::: "memory");
        __builtin_amdgcn_sched_barrier(0);
    }
}

extern "C" void kernel_launch(void* const* d_in, const int* in_sizes, int n_in,
                              void* d_out, int out_size, void* d_ws, size_t ws_size,
                              hipStream_t stream) {
    const float* x   = (const float*)d_in[0];
    const int*   ei  = (const int*)d_in[1];
    const float* W1l = (const float*)d_in[2];
    const float* b1  = (const float*)d_in[3];
    const float* W1r = (const float*)d_in[4];
    const float* W2l = (const float*)d_in[5];
    const float* b2  = (const float*)d_in[6];
    const float* W2r = (const float*)d_in[7];
    float* out = (float*)d_out;

    const int N = in_sizes[0] / 256;   // 50000
    const int E = in_sizes[1] / 2;     // 800000
    const int* src = ei;
    const int* dst = ei + E;

    char* ws = (char*)d_ws;
    size_t off = 0;
    auto alloc = [&](size_t bytes) -> void* {
        void* p = ws + off;
        off += (bytes + 255) & ~(size_t)255;
        return p;
    };
    int* cnt  = (int*)alloc((size_t)N * 4);
    unsigned short* colp = (unsigned short*)alloc((size_t)N * CAP * 2);   // uint16 (r12)
    unsigned short* xb  = (unsigned short*)alloc((size_t)N * 256 * 2);
    unsigned short* hb  = (unsigned short*)alloc((size_t)N * 256 * 2);
    unsigned short* mb  = (unsigned short*)alloc((size_t)N * 256 * 2);
    unsigned char*  xb8 = (unsigned char*)alloc((size_t)(N + 1) * 256);   // +zero row
    unsigned char*  hb8 = (unsigned char*)alloc((size_t)(N + 1) * 256);   // +zero row
    unsigned short* Bt1 = (unsigned short*)alloc((size_t)256 * 512 * 2);
    unsigned short* Bt2 = (unsigned short*)alloc((size_t)256 * 512 * 2);

    // cnt zeroing: stream-ordered memset BEFORE the merged prep
    hipMemsetAsync(cnt, 0, (size_t)N * 4, stream);

    // merged prep: edge-pass first (latency-bound, co-resides with BW blocks)
    const int n4 = N * 256 / 4;
    const int nbc = (n4 + 255) / 256;
    const int nbe = (E + 1023) / 1024;
    prep_kernel<<<nbe + nbc + 1024 + 1, 256, 0, stream>>>(src, dst, E, nbe, cnt, colp,
                                                          x, xb, xb8, n4, nbc,
                                                          W1l, W1r, Bt1, W2l, W2r, Bt2,
                                                          N, hb8);

    const int mtiles = (N + 127) / 128;
    dim3 ggrid(mtiles, 2);
    const int ablocks = (N + 3) / 4;

    // layer 1: mean(x) -> mb; h = relu([mb|xb] @ Bt1 + b1) -> hb (bf16) + hb8 (fp8)
    aggregate_kernel<<<ablocks, 256, 0, stream>>>(xb8, cnt, colp, mb, N);
    gemm_kernel<1><<<ggrid, 256, 0, stream>>>(mb, xb, Bt1, b1, nullptr, hb, hb8, N);

    // layer 2: mean(h) -> mb; out = [mb|hb] @ Bt2 + b2 (fp32)
    aggregate_kernel<<<ablocks, 256, 0, stream>>>(hb8, cnt, colp, mb, N);
    gemm_kernel<0><<<ggrid, 256, 0, stream>>>(mb, hb, Bt2, b2, out, nullptr, nullptr, N);
}